// Round 3
// baseline (438.063 us; speedup 1.0000x reference)
//
#include <hip/hip_runtime.h>
#include <hip/hip_bf16.h>

#define BB 2
#define NN 384
#define TFD 22
#define POSD 32
#define TPROJ 33
#define CS 256
#define CZ 128
#define PI_F 3.14159265358979323846f

typedef __hip_bfloat16 bf16;
typedef __attribute__((ext_vector_type(8))) short short8;
typedef __attribute__((ext_vector_type(4))) float floatx4;

__device__ __forceinline__ float bfbits2f(unsigned short u) {
  unsigned v = ((unsigned)u) << 16;
  float f;
  __builtin_memcpy(&f, &v, 4);
  return f;
}
__device__ __forceinline__ unsigned short f2bf(float x) {
  bf16 h = __float2bfloat16(x);
  unsigned short u;
  __builtin_memcpy(&u, &h, 2);
  return u;
}
__device__ __forceinline__ bool probe_f32(const void* fm) {
  return *(const unsigned*)fm == 0x3F800000u;
}
__device__ __forceinline__ float ldraw(const void* p, int i, bool f32) {
  return f32 ? ((const float*)p)[i] : bfbits2f(((const unsigned short*)p)[i]);
}

// ---- ws layout (float units) ----
#define TAB_OFF 0            // 2048*128 (tab incl. all three edge biases)
#define SEQ0_OFF 262144      // 768*256
#define EL_OFF 458752        // 768*128
#define ER_OFF 557056        // 768*128
#define P_OFF 655360         // fp32 params, 60802
#define WB_OFF 716288        // bf16 (ushort) weight region: 163840 ushorts
// param-relative offsets
#define pSEQF 0
#define pTS 16896
#define pFM 16898
#define pWNPOS 17666
#define pBNPOS 25858
#define pWNTF 26114
#define pBNTF 31746
#define pWNTIME 32002
#define pBNTIME 40450
#define pBN1 40706
#define pBN2 40962
#define pGN 41218
#define pBEN 41474
#define pWEPOS 41730
#define pBEPOS 45826
#define pWETF 45954
#define pBETF 51586
#define pWETIME 51714
#define pBETIME 60162
#define pBE1 60290
#define pBE2 60418
#define pGE 60546
#define pBEE 60674
// ushort-relative offsets in WB region
#define UB_WE1 0
#define UB_WE2 16384
#define UB_WN1 32768
#define UB_WN2 98304

#define NB_CVT 878
#define NB_TAB 1024
#define NB_NODEPREP 768

struct InPtrs { const void* p[28]; };

__device__ const int g_srci[27] = {1,2,3,4,5,6,7,8,9,11,13,14,15,16,17,18,19,20,21,23,25,26,27,22,24,10,12};
__device__ const int g_pre[28] = {0,16896,16898,17666,25858,26114,31746,32002,40450,40706,40962,41218,41474,
                                  41730,45826,45954,51586,51714,60162,60290,60418,60546,60674,60802,
                                  77186,93570,159106,224642};
__device__ const int g_ub[4] = {UB_WE1, UB_WE2, UB_WN1, UB_WN2};

// Fused prep: [0,878) param convert | [878,1902) rel-table | [1902,2670) per-node.
// All sections read only raw inputs -> no inter-section dependency.
__global__ __launch_bounds__(256) void prep(InPtrs ip, const int* __restrict__ seq_idx,
                                            float* __restrict__ ws) {
  const bool f32 = probe_f32(ip.p[3]);
  const int t = threadIdx.x;
  int sb = blockIdx.x;
  if (sb < NB_CVT) {
    int idx = sb * 256 + t;
    if (idx >= 224642) return;
    int e = 0;
    while (idx >= g_pre[e + 1]) ++e;
    int j = idx - g_pre[e];
    const void* sp = ip.p[g_srci[e]];
    if (e < 23) {
      ws[P_OFF + g_pre[e] + j] = ldraw(sp, j, f32);
    } else {
      unsigned short* wb = (unsigned short*)(ws + WB_OFF);
      wb[g_ub[e - 23] + j] = f32 ? f2bf(((const float*)sp)[j]) : ((const unsigned short*)sp)[j];
    }
    return;
  }
  sb -= NB_CVT;
  if (sb < NB_TAB) {
    __shared__ float pe[2][POSD];
    int half = t >> 7, tc = t & 127;
    int r = sb * 2 + half;
    if (tc < 16) {
      float ang = (float)(r - 1024) * PI_F * powf(2056.0f, -(float)tc * (1.0f / 16.0f));
      pe[half][tc] = sinf(ang);
      pe[half][tc + 16] = cosf(ang);
    }
    __syncthreads();
    float acc = ldraw(ip.p[17], tc, f32) + ldraw(ip.p[19], tc, f32) + ldraw(ip.p[21], tc, f32);
#pragma unroll
    for (int k = 0; k < POSD; ++k) acc += pe[half][k] * ldraw(ip.p[16], tc * POSD + k, f32);
    ws[TAB_OFF + r * CZ + tc] = acc;
    return;
  }
  sb -= NB_TAB;
  {
    __shared__ float pe[POSD];
    __shared__ float temb[TPROJ];
    __shared__ float sf[TFD];
    int bn = sb, b = bn / NN;
    float fm = ldraw(ip.p[3], bn, f32);
    if (t < 16) {
      float idxv = (float)seq_idx[bn];
      float ang = idxv * PI_F * powf(2056.0f, -(float)t * (1.0f / 16.0f));
      pe[t] = sinf(ang);
      pe[t + 16] = cosf(ang);
      float tres = ldraw(ip.p[2], b, f32) * fm;
      float freq = expf(-(logf(10000.0f) * (1.0f / 15.0f)) * (float)t);
      temb[t] = sinf(tres * freq);
      temb[t + 16] = cosf(tres * freq);
    }
    if (t == 16) temb[32] = fm;
    if (t < TFD) sf[t] = ldraw(ip.p[1], bn * TFD + t, f32);
    __syncthreads();
    {
      int c = t;
      float acc = ldraw(ip.p[5], c, f32) + ldraw(ip.p[7], c, f32) + ldraw(ip.p[9], c, f32);
#pragma unroll
      for (int k = 0; k < POSD; ++k) acc += pe[k] * ldraw(ip.p[4], c * POSD + k, f32);
#pragma unroll
      for (int k = 0; k < TFD; ++k) acc += sf[k] * ldraw(ip.p[6], c * TFD + k, f32);
#pragma unroll
      for (int k = 0; k < TPROJ; ++k) acc += temb[k] * ldraw(ip.p[8], c * TPROJ + k, f32);
      ws[SEQ0_OFF + bn * CS + c] = acc;
    }
    if (t < CZ) {
      int c = t;
      float acc = 0.0f;
#pragma unroll
      for (int k = 0; k < TFD; ++k) acc += sf[k] * ldraw(ip.p[18], c * (2 * TFD) + k, f32);
#pragma unroll
      for (int k = 0; k < TPROJ; ++k) acc += temb[k] * ldraw(ip.p[20], c * (2 * TPROJ) + k, f32);
      ws[EL_OFF + bn * CZ + c] = acc;
    } else {
      int c = t - CZ;
      float acc = 0.0f;
#pragma unroll
      for (int k = 0; k < TFD; ++k) acc += sf[k] * ldraw(ip.p[18], c * (2 * TFD) + TFD + k, f32);
#pragma unroll
      for (int k = 0; k < TPROJ; ++k) acc += temb[k] * ldraw(ip.p[20], c * (2 * TPROJ) + TPROJ + k, f32);
      ws[ER_OFF + bn * CZ + c] = acc;
    }
  }
}

// ---- Node MLP via MFMA (proven round-2 code): 32 rows/block, C=256, 2 layers + LN. ----
__global__ __launch_bounds__(256) void node_mfma(const float* __restrict__ ws,
                                                 const void* __restrict__ fmraw,
                                                 void* __restrict__ outv) {
  __shared__ __align__(16) unsigned short sA0[32][CS + 8];
  __shared__ __align__(16) unsigned short sA1[32][CS + 8];
  __shared__ float sO[32][CS + 4];
  __shared__ float sRed[32][8], sRedQ[32][8], sMu[32], sRs[32];
  const float* P = ws + P_OFF;
  const unsigned short* WB = (const unsigned short*)(ws + WB_OFF);
  const unsigned short* W1 = WB + UB_WN1;
  const unsigned short* W2 = WB + UB_WN2;
  const int row0 = blockIdx.x * 32;
  const int t = threadIdx.x;
  const int wave = t >> 6, lane = t & 63, quad = lane >> 4, l16 = lane & 15;
  {
    const float* seq0 = ws + SEQ0_OFF;
#pragma unroll
    for (int r = 0; r < 32; ++r) sA0[r][t] = f2bf(fmaxf(seq0[(row0 + r) * CS + t], 0.0f));
  }
  __syncthreads();
  short8 af[2][8];
  floatx4 acc[2][4];
#pragma unroll
  for (int mt = 0; mt < 2; ++mt)
#pragma unroll
    for (int ks = 0; ks < 8; ++ks)
      af[mt][ks] = *(const short8*)&sA0[mt * 16 + l16][ks * 32 + quad * 8];
#pragma unroll
  for (int mt = 0; mt < 2; ++mt)
#pragma unroll
    for (int n = 0; n < 4; ++n) acc[mt][n] = (floatx4){0.f, 0.f, 0.f, 0.f};
#pragma unroll
  for (int ntl = 0; ntl < 4; ++ntl) {
    int n0 = (wave * 4 + ntl) * 16;
#pragma unroll
    for (int ks = 0; ks < 8; ++ks) {
      short8 bfr = *(const short8*)&W1[(n0 + l16) * CS + ks * 32 + quad * 8];
      acc[0][ntl] = __builtin_amdgcn_mfma_f32_16x16x32_bf16(af[0][ks], bfr, acc[0][ntl], 0, 0, 0);
      acc[1][ntl] = __builtin_amdgcn_mfma_f32_16x16x32_bf16(af[1][ks], bfr, acc[1][ntl], 0, 0, 0);
    }
  }
#pragma unroll
  for (int ntl = 0; ntl < 4; ++ntl) {
    int n0 = (wave * 4 + ntl) * 16;
    float b1v = P[pBN1 + n0 + l16];
#pragma unroll
    for (int mt = 0; mt < 2; ++mt)
#pragma unroll
      for (int i = 0; i < 4; ++i)
        sA1[mt * 16 + quad * 4 + i][n0 + l16] = f2bf(fmaxf(acc[mt][ntl][i] + b1v, 0.0f));
  }
  __syncthreads();
#pragma unroll
  for (int mt = 0; mt < 2; ++mt)
#pragma unroll
    for (int ks = 0; ks < 8; ++ks)
      af[mt][ks] = *(const short8*)&sA1[mt * 16 + l16][ks * 32 + quad * 8];
#pragma unroll
  for (int mt = 0; mt < 2; ++mt)
#pragma unroll
    for (int n = 0; n < 4; ++n) acc[mt][n] = (floatx4){0.f, 0.f, 0.f, 0.f};
#pragma unroll
  for (int ntl = 0; ntl < 4; ++ntl) {
    int n0 = (wave * 4 + ntl) * 16;
#pragma unroll
    for (int ks = 0; ks < 8; ++ks) {
      short8 bfr = *(const short8*)&W2[(n0 + l16) * CS + ks * 32 + quad * 8];
      acc[0][ntl] = __builtin_amdgcn_mfma_f32_16x16x32_bf16(af[0][ks], bfr, acc[0][ntl], 0, 0, 0);
      acc[1][ntl] = __builtin_amdgcn_mfma_f32_16x16x32_bf16(af[1][ks], bfr, acc[1][ntl], 0, 0, 0);
    }
  }
#pragma unroll
  for (int ntl = 0; ntl < 4; ++ntl) {
    int n0 = (wave * 4 + ntl) * 16;
    float b2v = P[pBN2 + n0 + l16];
#pragma unroll
    for (int mt = 0; mt < 2; ++mt)
#pragma unroll
      for (int i = 0; i < 4; ++i)
        sO[mt * 16 + quad * 4 + i][n0 + l16] = acc[mt][ntl][i] + b2v;
  }
  __syncthreads();
  {
    int r = t >> 3, seg = t & 7;
    float s = 0.f, q = 0.f;
#pragma unroll
    for (int k = 0; k < 32; ++k) { float v = sO[r][seg * 32 + k]; s += v; q += v * v; }
    sRed[r][seg] = s; sRedQ[r][seg] = q;
  }
  __syncthreads();
  if (t < 32) {
    float s = 0.f, q = 0.f;
#pragma unroll
    for (int k = 0; k < 8; ++k) { s += sRed[t][k]; q += sRedQ[t][k]; }
    float mu = s * (1.0f / CS);
    float var = q * (1.0f / CS) - mu * mu;
    sMu[t] = mu; sRs[t] = rsqrtf(var + 1e-5f);
  }
  __syncthreads();
  {
    float g = P[pGN + t], be = P[pBEN + t];
    if (probe_f32(fmraw)) {
      float* o = (float*)outv;
#pragma unroll
      for (int r = 0; r < 32; ++r)
        o[(size_t)(row0 + r) * CS + t] = (sO[r][t] - sMu[r]) * sRs[r] * g + be;
    } else {
      bf16* o = (bf16*)outv;
#pragma unroll
      for (int r = 0; r < 32; ++r)
        o[(size_t)(row0 + r) * CS + t] = __float2bfloat16((sO[r][t] - sMu[r]) * sRs[r] * g + be);
    }
  }
}

// ---- Edge v2: barrier-free. Block = (b, i, 64 j's); each wave owns 16 edges. ----
// Layer 1/2 computed transposed (A = weights, B = activations), so LN reduces via shfl.
__global__ __launch_bounds__(256) void edge_mfma(const int* __restrict__ seq_idx,
                                                 const float* __restrict__ ws,
                                                 const void* __restrict__ fmraw,
                                                 void* __restrict__ outv) {
  __shared__ unsigned short H2[4][16][136];  // wave-private transpose buffer
  const float* tab = ws + TAB_OFF;
  const float* eL = ws + EL_OFF;
  const float* eR = ws + ER_OFF;
  const float* P = ws + P_OFF;
  const unsigned short* W1 = (const unsigned short*)(ws + WB_OFF) + UB_WE1;
  const unsigned short* W2 = (const unsigned short*)(ws + WB_OFF) + UB_WE2;
  const int bid = blockIdx.x;
  const int jt = bid % (NN / 64);
  const int rem = bid / (NN / 64);
  const int irow = rem % NN;
  const int b = rem / NN;
  const int t = threadIdx.x;
  const int w = t >> 6, lane = t & 63, quad = lane >> 4, l16 = lane & 15;
  const int j = jt * 64 + w * 16 + l16;
  int rel = seq_idx[b * NN + irow] - seq_idx[b * NN + j] + 1024;
  rel = min(max(rel, 0), 2047);
  // ---- build A0 frags straight from global (no LDS, no barrier) ----
  union U8 { short8 v; unsigned short u[8]; };
  short8 af[4];
  const float* tabr = tab + rel * CZ;
  const float* eRr = eR + (b * NN + j) * CZ;
  const float* eLr = eL + (b * NN + irow) * CZ;
#pragma unroll
  for (int ks = 0; ks < 4; ++ks) {
    int c0 = ks * 32 + quad * 8;
    float4 t0 = *(const float4*)(tabr + c0), t1 = *(const float4*)(tabr + c0 + 4);
    float4 r0 = *(const float4*)(eRr + c0), r1 = *(const float4*)(eRr + c0 + 4);
    float4 l0 = *(const float4*)(eLr + c0), l1 = *(const float4*)(eLr + c0 + 4);
    U8 a;
    a.u[0] = f2bf(fmaxf(t0.x + r0.x + l0.x, 0.f));
    a.u[1] = f2bf(fmaxf(t0.y + r0.y + l0.y, 0.f));
    a.u[2] = f2bf(fmaxf(t0.z + r0.z + l0.z, 0.f));
    a.u[3] = f2bf(fmaxf(t0.w + r0.w + l0.w, 0.f));
    a.u[4] = f2bf(fmaxf(t1.x + r1.x + l1.x, 0.f));
    a.u[5] = f2bf(fmaxf(t1.y + r1.y + l1.y, 0.f));
    a.u[6] = f2bf(fmaxf(t1.z + r1.z + l1.z, 0.f));
    a.u[7] = f2bf(fmaxf(t1.w + r1.w + l1.w, 0.f));
    af[ks] = a.v;
  }
  // ---- layer 1: C1^T = W1 * A0^T ----
  floatx4 acc1[8];
#pragma unroll
  for (int mt = 0; mt < 8; ++mt) {
    acc1[mt] = (floatx4){0.f, 0.f, 0.f, 0.f};
#pragma unroll
    for (int ks = 0; ks < 4; ++ks) {
      short8 wf = *(const short8*)&W1[(mt * 16 + l16) * CZ + ks * 32 + quad * 8];
      acc1[mt] = __builtin_amdgcn_mfma_f32_16x16x32_bf16(wf, af[ks], acc1[mt], 0, 0, 0);
    }
  }
  // ---- bias+relu, wave-private LDS transpose (no __syncthreads) ----
#pragma unroll
  for (int mt = 0; mt < 8; ++mt) {
    float4 b1 = *(const float4*)&P[pBE1 + mt * 16 + quad * 4];
    unsigned u0 = f2bf(fmaxf(acc1[mt][0] + b1.x, 0.f));
    unsigned u1 = f2bf(fmaxf(acc1[mt][1] + b1.y, 0.f));
    unsigned u2 = f2bf(fmaxf(acc1[mt][2] + b1.z, 0.f));
    unsigned u3 = f2bf(fmaxf(acc1[mt][3] + b1.w, 0.f));
    uint2 pk;
    pk.x = u0 | (u1 << 16);
    pk.y = u2 | (u3 << 16);
    *(uint2*)&H2[w][l16][mt * 16 + quad * 4] = pk;
  }
  short8 bf2[4];
#pragma unroll
  for (int ks = 0; ks < 4; ++ks)
    bf2[ks] = *(const short8*)&H2[w][l16][ks * 32 + quad * 8];
  // ---- layer 2: C2^T = W2 * H ----
  floatx4 acc2[8];
#pragma unroll
  for (int mt = 0; mt < 8; ++mt) {
    acc2[mt] = (floatx4){0.f, 0.f, 0.f, 0.f};
#pragma unroll
    for (int ks = 0; ks < 4; ++ks) {
      short8 wf = *(const short8*)&W2[(mt * 16 + l16) * CZ + ks * 32 + quad * 8];
      acc2[mt] = __builtin_amdgcn_mfma_f32_16x16x32_bf16(wf, bf2[ks], acc2[mt], 0, 0, 0);
    }
  }
  // ---- bias + LN stats in registers ----
  float s = 0.f, q = 0.f;
#pragma unroll
  for (int mt = 0; mt < 8; ++mt) {
    float4 b2 = *(const float4*)&P[pBE2 + mt * 16 + quad * 4];
    acc2[mt][0] += b2.x; acc2[mt][1] += b2.y; acc2[mt][2] += b2.z; acc2[mt][3] += b2.w;
#pragma unroll
    for (int i = 0; i < 4; ++i) { float v = acc2[mt][i]; s += v; q += v * v; }
  }
  s += __shfl_xor(s, 16, 64); q += __shfl_xor(q, 16, 64);
  s += __shfl_xor(s, 32, 64); q += __shfl_xor(q, 32, 64);
  float mu = s * (1.0f / CZ);
  float rs = rsqrtf(q * (1.0f / CZ) - mu * mu + 1e-5f);
  // ---- scale & store ----
  size_t base = ((size_t)(b * NN + irow) * NN + j) * CZ;
  if (probe_f32(fmraw)) {
    float* o = (float*)outv + (size_t)BB * NN * CS;
#pragma unroll
    for (int mt = 0; mt < 8; ++mt) {
      int c0 = mt * 16 + quad * 4;
      float4 g4 = *(const float4*)&P[pGE + c0];
      float4 be4 = *(const float4*)&P[pBEE + c0];
      float4 o4;
      o4.x = (acc2[mt][0] - mu) * rs * g4.x + be4.x;
      o4.y = (acc2[mt][1] - mu) * rs * g4.y + be4.y;
      o4.z = (acc2[mt][2] - mu) * rs * g4.z + be4.z;
      o4.w = (acc2[mt][3] - mu) * rs * g4.w + be4.w;
      *(float4*)(o + base + c0) = o4;
    }
  } else {
    unsigned short* o = (unsigned short*)outv + (size_t)BB * NN * CS;
#pragma unroll
    for (int mt = 0; mt < 8; ++mt) {
      int c0 = mt * 16 + quad * 4;
      float4 g4 = *(const float4*)&P[pGE + c0];
      float4 be4 = *(const float4*)&P[pBEE + c0];
      unsigned u0 = f2bf((acc2[mt][0] - mu) * rs * g4.x + be4.x);
      unsigned u1 = f2bf((acc2[mt][1] - mu) * rs * g4.y + be4.y);
      unsigned u2 = f2bf((acc2[mt][2] - mu) * rs * g4.z + be4.z);
      unsigned u3 = f2bf((acc2[mt][3] - mu) * rs * g4.w + be4.w);
      uint2 pk;
      pk.x = u0 | (u1 << 16);
      pk.y = u2 | (u3 << 16);
      *(uint2*)(o + base + c0) = pk;
    }
  }
}

extern "C" void kernel_launch(void* const* d_in, const int* in_sizes, int n_in,
                              void* d_out, int out_size, void* d_ws, size_t ws_size,
                              hipStream_t stream) {
  (void)in_sizes; (void)n_in; (void)out_size; (void)ws_size;
  const int* seq_idx = (const int*)d_in[0];
  float* ws = (float*)d_ws;
  InPtrs ip;
  for (int i = 0; i < 28; ++i) ip.p[i] = d_in[i];
  hipLaunchKernelGGL(prep, dim3(NB_CVT + NB_TAB + NB_NODEPREP), dim3(256), 0, stream,
                     ip, seq_idx, ws);
  hipLaunchKernelGGL(edge_mfma, dim3(BB * NN * (NN / 64)), dim3(256), 0, stream,
                     seq_idx, ws, d_in[3], d_out);
  hipLaunchKernelGGL(node_mfma, dim3(BB * NN / 32), dim3(256), 0, stream, ws, d_in[3], d_out);
}

// Round 4
// 325.787 us; speedup vs baseline: 1.3446x; 1.3446x over previous
//
#include <hip/hip_runtime.h>
#include <hip/hip_bf16.h>

#define BB 2
#define NN 384
#define TFD 22
#define POSD 32
#define TPROJ 33
#define CS 256
#define CZ 128
#define PI_F 3.14159265358979323846f

typedef __hip_bfloat16 bf16;
typedef __attribute__((ext_vector_type(8))) short short8;
typedef __attribute__((ext_vector_type(4))) float floatx4;

__device__ __forceinline__ float bfbits2f(unsigned short u) {
  unsigned v = ((unsigned)u) << 16;
  float f;
  __builtin_memcpy(&f, &v, 4);
  return f;
}
__device__ __forceinline__ unsigned short f2bf(float x) {
  bf16 h = __float2bfloat16(x);
  unsigned short u;
  __builtin_memcpy(&u, &h, 2);
  return u;
}
__device__ __forceinline__ bool probe_f32(const void* fm) {
  return *(const unsigned*)fm == 0x3F800000u;
}
__device__ __forceinline__ float ldraw(const void* p, int i, bool f32) {
  return f32 ? ((const float*)p)[i] : bfbits2f(((const unsigned short*)p)[i]);
}

// ---- ws layout (float units) ----
#define TAB_OFF 0            // 2048*128
#define SEQ0_OFF 262144      // 768*256
#define EL_OFF 458752        // 768*128
#define ER_OFF 557056        // 768*128
#define P_OFF 655360         // fp32 params + transposed copies: 101250 floats
#define WB_OFF 756612        // bf16 (ushort) weights: 163840 ushorts (16B-aligned)
// param-relative offsets (P region)
#define pSEQF 0
#define pTS 16896
#define pFM 16898
#define pBNPOS 25858
#define pBNTF 31746
#define pBNTIME 40450
#define pBN1 40706
#define pBN2 40962
#define pGN 41218
#define pBEN 41474
#define pBEPOS 45826
#define pBETF 51586
#define pBETIME 60162
#define pBE1 60290
#define pBE2 60418
#define pGE 60546
#define pBEE 60674
// transposed weights (WT[k][c])
#define pT_NPOS 60802
#define pT_NTF 68994
#define pT_NTIME 74626
#define pT_EPOS 83074
#define pT_ETF 87170
#define pT_ETIME 92802
// ushort-relative offsets in WB region
#define UB_WE1 0
#define UB_WE2 16384
#define UB_WN1 32768
#define UB_WN2 98304

#define NB_P1 1036
#define NB_TAB 1024
#define NB_NODE 768

struct InPtrs { const void* p[28]; };

__device__ const int g_srci[33] = {1,2,3,4,5,6,7,8,9,11,13,14,15,16,17,18,19,20,21,23,25,26,27,
                                   22,24,10,12, 4,6,8,16,18,20};
__device__ const int g_pre[34] = {0,16896,16898,17666,25858,26114,31746,32002,40450,40706,40962,41218,41474,
                                  41730,45826,45954,51586,51714,60162,60290,60418,60546,60674,
                                  60802,77186,93570,159106,
                                  224642,232834,238466,246914,251010,256642,265090};
__device__ const int g_ub[4] = {UB_WE1, UB_WE2, UB_WN1, UB_WN2};
__device__ const int g_tdst[6] = {pT_NPOS, pT_NTF, pT_NTIME, pT_EPOS, pT_ETF, pT_ETIME};
__device__ const int g_tL[6] = {32, 22, 33, 32, 44, 66};
__device__ const int g_tsh[6] = {8, 8, 8, 7, 7, 7};

// prep1: convert params -> P (fp32), transpose 6 embed weights -> P, convert+swizzle
// the 4 MLP weights -> WB. Reads RAW inputs only (section-order independent).
__global__ __launch_bounds__(256) void prep1(InPtrs ip, float* __restrict__ ws) {
  const bool f32 = probe_f32(ip.p[3]);
  const int idx = blockIdx.x * 256 + threadIdx.x;
  if (idx >= 265090) return;
  int e = 0;
  while (idx >= g_pre[e + 1]) ++e;
  const int j = idx - g_pre[e];
  const void* sp = ip.p[g_srci[e]];
  if (e < 23) {
    ws[P_OFF + g_pre[e] + j] = ldraw(sp, j, f32);
  } else if (e < 27) {
    unsigned short* wb = (unsigned short*)(ws + WB_OFF);
    int src = j;
    if (e < 25) {  // fragment-major swizzle for edge weights
      int f = j >> 9, lane = (j >> 3) & 63, el = j & 7;
      int mt = f >> 2, ks = f & 3, qd = lane >> 4, l16 = lane & 15;
      src = (mt * 16 + l16) * CZ + ks * 32 + qd * 8 + el;
    }
    wb[g_ub[e - 23] + j] = f32 ? f2bf(((const float*)sp)[src]) : ((const unsigned short*)sp)[src];
  } else {
    int m = e - 27;
    int sh = g_tsh[m];
    int k = j >> sh, c = j & ((1 << sh) - 1);
    ws[P_OFF + g_tdst[m] + j] = ldraw(sp, c * g_tL[m] + k, f32);
  }
}

// prep2: [0,1024) rel-table rows | [1024,1792) per-node seq0/eL/eR. Reads P (prep1 output).
__global__ __launch_bounds__(256) void prep2(InPtrs ip, const int* __restrict__ seq_idx,
                                             float* __restrict__ ws) {
  const bool f32 = probe_f32(ip.p[3]);
  const float* P = ws + P_OFF;
  const int t = threadIdx.x;
  int sb = blockIdx.x;
  if (sb < NB_TAB) {
    __shared__ float pe[2][POSD];
    int half = t >> 7, tc = t & 127;
    int r = sb * 2 + half;
    if (tc < 16) {
      float ang = (float)(r - 1024) * PI_F * powf(2056.0f, -(float)tc * (1.0f / 16.0f));
      pe[half][tc] = sinf(ang);
      pe[half][tc + 16] = cosf(ang);
    }
    __syncthreads();
    float acc = P[pBEPOS + tc] + P[pBETF + tc] + P[pBETIME + tc];
#pragma unroll
    for (int k = 0; k < POSD; ++k) acc += pe[half][k] * P[pT_EPOS + k * CZ + tc];
    ws[TAB_OFF + r * CZ + tc] = acc;
    return;
  }
  sb -= NB_TAB;
  {
    __shared__ float pe[POSD];
    __shared__ float temb[TPROJ];
    __shared__ float sf[TFD];
    int bn = sb, b = bn / NN;
    float fm = P[pFM + bn];
    if (t < 16) {
      float idxv = (float)seq_idx[bn];
      float ang = idxv * PI_F * powf(2056.0f, -(float)t * (1.0f / 16.0f));
      pe[t] = sinf(ang);
      pe[t + 16] = cosf(ang);
      float tres = P[pTS + b] * fm;
      float freq = expf(-(logf(10000.0f) * (1.0f / 15.0f)) * (float)t);
      temb[t] = sinf(tres * freq);
      temb[t + 16] = cosf(tres * freq);
    }
    if (t == 16) temb[32] = fm;
    if (t < TFD) sf[t] = P[pSEQF + bn * TFD + t];
    __syncthreads();
    {
      int c = t;  // 0..255
      float acc = P[pBNPOS + c] + P[pBNTF + c] + P[pBNTIME + c];
#pragma unroll
      for (int k = 0; k < POSD; ++k) acc += pe[k] * P[pT_NPOS + k * CS + c];
#pragma unroll
      for (int k = 0; k < TFD; ++k) acc += sf[k] * P[pT_NTF + k * CS + c];
#pragma unroll
      for (int k = 0; k < TPROJ; ++k) acc += temb[k] * P[pT_NTIME + k * CS + c];
      ws[SEQ0_OFF + bn * CS + c] = acc;
    }
    if (t < CZ) {
      int c = t;
      float acc = 0.0f;
#pragma unroll
      for (int k = 0; k < TFD; ++k) acc += sf[k] * P[pT_ETF + k * CZ + c];
#pragma unroll
      for (int k = 0; k < TPROJ; ++k) acc += temb[k] * P[pT_ETIME + k * CZ + c];
      ws[EL_OFF + bn * CZ + c] = acc;
    } else {
      int c = t - CZ;
      float acc = 0.0f;
#pragma unroll
      for (int k = 0; k < TFD; ++k) acc += sf[k] * P[pT_ETF + (22 + k) * CZ + c];
#pragma unroll
      for (int k = 0; k < TPROJ; ++k) acc += temb[k] * P[pT_ETIME + (33 + k) * CZ + c];
      ws[ER_OFF + bn * CZ + c] = acc;
    }
  }
}

// ---- Node MLP via MFMA (proven round-2 code): 32 rows/block, C=256, 2 layers + LN. ----
__global__ __launch_bounds__(256) void node_mfma(const float* __restrict__ ws,
                                                 const void* __restrict__ fmraw,
                                                 void* __restrict__ outv) {
  __shared__ __align__(16) unsigned short sA0[32][CS + 8];
  __shared__ __align__(16) unsigned short sA1[32][CS + 8];
  __shared__ float sO[32][CS + 4];
  __shared__ float sRed[32][8], sRedQ[32][8], sMu[32], sRs[32];
  const float* P = ws + P_OFF;
  const unsigned short* WB = (const unsigned short*)(ws + WB_OFF);
  const unsigned short* W1 = WB + UB_WN1;
  const unsigned short* W2 = WB + UB_WN2;
  const int row0 = blockIdx.x * 32;
  const int t = threadIdx.x;
  const int wave = t >> 6, lane = t & 63, quad = lane >> 4, l16 = lane & 15;
  {
    const float* seq0 = ws + SEQ0_OFF;
#pragma unroll
    for (int r = 0; r < 32; ++r) sA0[r][t] = f2bf(fmaxf(seq0[(row0 + r) * CS + t], 0.0f));
  }
  __syncthreads();
  short8 af[2][8];
  floatx4 acc[2][4];
#pragma unroll
  for (int mt = 0; mt < 2; ++mt)
#pragma unroll
    for (int ks = 0; ks < 8; ++ks)
      af[mt][ks] = *(const short8*)&sA0[mt * 16 + l16][ks * 32 + quad * 8];
#pragma unroll
  for (int mt = 0; mt < 2; ++mt)
#pragma unroll
    for (int n = 0; n < 4; ++n) acc[mt][n] = (floatx4){0.f, 0.f, 0.f, 0.f};
#pragma unroll
  for (int ntl = 0; ntl < 4; ++ntl) {
    int n0 = (wave * 4 + ntl) * 16;
#pragma unroll
    for (int ks = 0; ks < 8; ++ks) {
      short8 bfr = *(const short8*)&W1[(n0 + l16) * CS + ks * 32 + quad * 8];
      acc[0][ntl] = __builtin_amdgcn_mfma_f32_16x16x32_bf16(af[0][ks], bfr, acc[0][ntl], 0, 0, 0);
      acc[1][ntl] = __builtin_amdgcn_mfma_f32_16x16x32_bf16(af[1][ks], bfr, acc[1][ntl], 0, 0, 0);
    }
  }
#pragma unroll
  for (int ntl = 0; ntl < 4; ++ntl) {
    int n0 = (wave * 4 + ntl) * 16;
    float b1v = P[pBN1 + n0 + l16];
#pragma unroll
    for (int mt = 0; mt < 2; ++mt)
#pragma unroll
      for (int i = 0; i < 4; ++i)
        sA1[mt * 16 + quad * 4 + i][n0 + l16] = f2bf(fmaxf(acc[mt][ntl][i] + b1v, 0.0f));
  }
  __syncthreads();
#pragma unroll
  for (int mt = 0; mt < 2; ++mt)
#pragma unroll
    for (int ks = 0; ks < 8; ++ks)
      af[mt][ks] = *(const short8*)&sA1[mt * 16 + l16][ks * 32 + quad * 8];
#pragma unroll
  for (int mt = 0; mt < 2; ++mt)
#pragma unroll
    for (int n = 0; n < 4; ++n) acc[mt][n] = (floatx4){0.f, 0.f, 0.f, 0.f};
#pragma unroll
  for (int ntl = 0; ntl < 4; ++ntl) {
    int n0 = (wave * 4 + ntl) * 16;
#pragma unroll
    for (int ks = 0; ks < 8; ++ks) {
      short8 bfr = *(const short8*)&W2[(n0 + l16) * CS + ks * 32 + quad * 8];
      acc[0][ntl] = __builtin_amdgcn_mfma_f32_16x16x32_bf16(af[0][ks], bfr, acc[0][ntl], 0, 0, 0);
      acc[1][ntl] = __builtin_amdgcn_mfma_f32_16x16x32_bf16(af[1][ks], bfr, acc[1][ntl], 0, 0, 0);
    }
  }
#pragma unroll
  for (int ntl = 0; ntl < 4; ++ntl) {
    int n0 = (wave * 4 + ntl) * 16;
    float b2v = P[pBN2 + n0 + l16];
#pragma unroll
    for (int mt = 0; mt < 2; ++mt)
#pragma unroll
      for (int i = 0; i < 4; ++i)
        sO[mt * 16 + quad * 4 + i][n0 + l16] = acc[mt][ntl][i] + b2v;
  }
  __syncthreads();
  {
    int r = t >> 3, seg = t & 7;
    float s = 0.f, q = 0.f;
#pragma unroll
    for (int k = 0; k < 32; ++k) { float v = sO[r][seg * 32 + k]; s += v; q += v * v; }
    sRed[r][seg] = s; sRedQ[r][seg] = q;
  }
  __syncthreads();
  if (t < 32) {
    float s = 0.f, q = 0.f;
#pragma unroll
    for (int k = 0; k < 8; ++k) { s += sRed[t][k]; q += sRedQ[t][k]; }
    float mu = s * (1.0f / CS);
    float var = q * (1.0f / CS) - mu * mu;
    sMu[t] = mu; sRs[t] = rsqrtf(var + 1e-5f);
  }
  __syncthreads();
  {
    float g = P[pGN + t], be = P[pBEN + t];
    if (probe_f32(fmraw)) {
      float* o = (float*)outv;
#pragma unroll
      for (int r = 0; r < 32; ++r)
        o[(size_t)(row0 + r) * CS + t] = (sO[r][t] - sMu[r]) * sRs[r] * g + be;
    } else {
      bf16* o = (bf16*)outv;
#pragma unroll
      for (int r = 0; r < 32; ++r)
        o[(size_t)(row0 + r) * CS + t] = __float2bfloat16((sO[r][t] - sMu[r]) * sRs[r] * g + be);
    }
  }
}

// ---- Edge v4: coalesced LDS staging (1 barrier) + swizzled-W frags + register LN. ----
// Block = (b, i, 64 j's); 4 waves, each owns 16 edges end-to-end after the barrier.
__global__ __launch_bounds__(256) void edge_mfma(const int* __restrict__ seq_idx,
                                                 const float* __restrict__ ws,
                                                 const void* __restrict__ fmraw,
                                                 void* __restrict__ outv) {
  __shared__ __align__(16) unsigned short sA0[64][136];
  __shared__ __align__(16) unsigned short H2[4][16][136];
  const float* tab = ws + TAB_OFF;
  const float* eL = ws + EL_OFF;
  const float* eR = ws + ER_OFF;
  const float* P = ws + P_OFF;
  const unsigned short* W1s = (const unsigned short*)(ws + WB_OFF) + UB_WE1;
  const unsigned short* W2s = (const unsigned short*)(ws + WB_OFF) + UB_WE2;
  const int bid = blockIdx.x;
  const int jt = bid % (NN / 64);
  const int rem = bid / (NN / 64);
  const int irow = rem % NN;
  const int b = rem / NN;
  const int j0 = jt * 64;
  const int t = threadIdx.x;
  const int w = t >> 6, lane = t & 63, quad = lane >> 4, l16 = lane & 15;
  // ---- coalesced staging: 8 thread-groups x 32 lanes cover (edge, 4 channels) ----
  {
    const int g = t >> 5, cq = t & 31, c0 = cq * 4;
    const float* eLr = eL + (b * NN + irow) * CZ;
    float4 l4 = *(const float4*)(eLr + c0);
    int si = seq_idx[b * NN + irow];
#pragma unroll
    for (int k = 0; k < 8; ++k) {
      int e = g + 8 * k;
      int j = j0 + e;
      int rel = si - seq_idx[b * NN + j] + 1024;
      rel = min(max(rel, 0), 2047);
      float4 t4 = *(const float4*)(tab + rel * CZ + c0);
      float4 r4 = *(const float4*)(eR + (b * NN + j) * CZ + c0);
      unsigned u0 = f2bf(fmaxf(t4.x + r4.x + l4.x, 0.f));
      unsigned u1 = f2bf(fmaxf(t4.y + r4.y + l4.y, 0.f));
      unsigned u2 = f2bf(fmaxf(t4.z + r4.z + l4.z, 0.f));
      unsigned u3 = f2bf(fmaxf(t4.w + r4.w + l4.w, 0.f));
      uint2 pk;
      pk.x = u0 | (u1 << 16);
      pk.y = u2 | (u3 << 16);
      *(uint2*)&sA0[e][c0] = pk;
    }
  }
  __syncthreads();
  // ---- A0 fragments from LDS ----
  short8 af[4];
#pragma unroll
  for (int ks = 0; ks < 4; ++ks)
    af[ks] = *(const short8*)&sA0[w * 16 + l16][ks * 32 + quad * 8];
  const int lbase = lane * 8;
  // ---- layer 1: C1^T = W1 * A0^T (W frags coalesced via swizzled layout) ----
  floatx4 acc1[8];
#pragma unroll
  for (int mt = 0; mt < 8; ++mt) {
    acc1[mt] = (floatx4){0.f, 0.f, 0.f, 0.f};
#pragma unroll
    for (int ks = 0; ks < 4; ++ks) {
      short8 wf = *(const short8*)&W1s[((mt * 4 + ks) << 9) + lbase];
      acc1[mt] = __builtin_amdgcn_mfma_f32_16x16x32_bf16(wf, af[ks], acc1[mt], 0, 0, 0);
    }
  }
  // ---- bias+relu, wave-private LDS transpose (no barrier) ----
#pragma unroll
  for (int mt = 0; mt < 8; ++mt) {
    float4 b1 = *(const float4*)&P[pBE1 + mt * 16 + quad * 4];
    unsigned u0 = f2bf(fmaxf(acc1[mt][0] + b1.x, 0.f));
    unsigned u1 = f2bf(fmaxf(acc1[mt][1] + b1.y, 0.f));
    unsigned u2 = f2bf(fmaxf(acc1[mt][2] + b1.z, 0.f));
    unsigned u3 = f2bf(fmaxf(acc1[mt][3] + b1.w, 0.f));
    uint2 pk;
    pk.x = u0 | (u1 << 16);
    pk.y = u2 | (u3 << 16);
    *(uint2*)&H2[w][l16][mt * 16 + quad * 4] = pk;
  }
  short8 bf2[4];
#pragma unroll
  for (int ks = 0; ks < 4; ++ks)
    bf2[ks] = *(const short8*)&H2[w][l16][ks * 32 + quad * 8];
  // ---- layer 2: C2^T = W2 * H ----
  floatx4 acc2[8];
#pragma unroll
  for (int mt = 0; mt < 8; ++mt) {
    acc2[mt] = (floatx4){0.f, 0.f, 0.f, 0.f};
#pragma unroll
    for (int ks = 0; ks < 4; ++ks) {
      short8 wf = *(const short8*)&W2s[((mt * 4 + ks) << 9) + lbase];
      acc2[mt] = __builtin_amdgcn_mfma_f32_16x16x32_bf16(wf, bf2[ks], acc2[mt], 0, 0, 0);
    }
  }
  // ---- bias + LN stats in registers ----
  float s = 0.f, q = 0.f;
#pragma unroll
  for (int mt = 0; mt < 8; ++mt) {
    float4 b2 = *(const float4*)&P[pBE2 + mt * 16 + quad * 4];
    acc2[mt][0] += b2.x; acc2[mt][1] += b2.y; acc2[mt][2] += b2.z; acc2[mt][3] += b2.w;
#pragma unroll
    for (int i = 0; i < 4; ++i) { float v = acc2[mt][i]; s += v; q += v * v; }
  }
  s += __shfl_xor(s, 16, 64); q += __shfl_xor(q, 16, 64);
  s += __shfl_xor(s, 32, 64); q += __shfl_xor(q, 32, 64);
  float mu = s * (1.0f / CZ);
  float rs = rsqrtf(q * (1.0f / CZ) - mu * mu + 1e-5f);
  // ---- scale & store (each 64B line fully covered by 4 quads) ----
  const int j = j0 + w * 16 + l16;
  size_t base = ((size_t)(b * NN + irow) * NN + j) * CZ;
  if (probe_f32(fmraw)) {
    float* o = (float*)outv + (size_t)BB * NN * CS;
#pragma unroll
    for (int mt = 0; mt < 8; ++mt) {
      int c0 = mt * 16 + quad * 4;
      float4 g4 = *(const float4*)&P[pGE + c0];
      float4 be4 = *(const float4*)&P[pBEE + c0];
      float4 o4;
      o4.x = (acc2[mt][0] - mu) * rs * g4.x + be4.x;
      o4.y = (acc2[mt][1] - mu) * rs * g4.y + be4.y;
      o4.z = (acc2[mt][2] - mu) * rs * g4.z + be4.z;
      o4.w = (acc2[mt][3] - mu) * rs * g4.w + be4.w;
      *(float4*)(o + base + c0) = o4;
    }
  } else {
    unsigned short* o = (unsigned short*)outv + (size_t)BB * NN * CS;
#pragma unroll
    for (int mt = 0; mt < 8; ++mt) {
      int c0 = mt * 16 + quad * 4;
      float4 g4 = *(const float4*)&P[pGE + c0];
      float4 be4 = *(const float4*)&P[pBEE + c0];
      unsigned u0 = f2bf((acc2[mt][0] - mu) * rs * g4.x + be4.x);
      unsigned u1 = f2bf((acc2[mt][1] - mu) * rs * g4.y + be4.y);
      unsigned u2 = f2bf((acc2[mt][2] - mu) * rs * g4.z + be4.z);
      unsigned u3 = f2bf((acc2[mt][3] - mu) * rs * g4.w + be4.w);
      uint2 pk;
      pk.x = u0 | (u1 << 16);
      pk.y = u2 | (u3 << 16);
      *(uint2*)(o + base + c0) = pk;
    }
  }
}

extern "C" void kernel_launch(void* const* d_in, const int* in_sizes, int n_in,
                              void* d_out, int out_size, void* d_ws, size_t ws_size,
                              hipStream_t stream) {
  (void)in_sizes; (void)n_in; (void)out_size; (void)ws_size;
  const int* seq_idx = (const int*)d_in[0];
  float* ws = (float*)d_ws;
  InPtrs ip;
  for (int i = 0; i < 28; ++i) ip.p[i] = d_in[i];
  hipLaunchKernelGGL(prep1, dim3(NB_P1), dim3(256), 0, stream, ip, ws);
  hipLaunchKernelGGL(prep2, dim3(NB_TAB + NB_NODE), dim3(256), 0, stream, ip, seq_idx, ws);
  hipLaunchKernelGGL(edge_mfma, dim3(BB * NN * (NN / 64)), dim3(256), 0, stream,
                     seq_idx, ws, d_in[3], d_out);
  hipLaunchKernelGGL(node_mfma, dim3(BB * NN / 32), dim3(256), 0, stream, ws, d_in[3], d_out);
}